// Round 5
// baseline (793.465 us; speedup 1.0000x reference)
//
#include <hip/hip_runtime.h>

// FactorizedSpectralConv: B=8, S1=S2=256, C=64, M1=M2=32.
// Fused per-dim kernels: truncated DFT (MFMA f16) -> complex mix (VALU fp32)
// -> iDFT (MFMA f16) -> block-staged epilogue with full-line contiguous stores.
//
// MFMA mapping discipline: logical k index f(g2,e) = 8*g2 + e is used for BOTH
// A (tables built by init kernel) and B (staging layout). C/D layout:
// col = lane&31, row = (reg&3) + 8*(reg>>2) + 4*(lane>>5)  [HW-verified].
//
// Epilogue lesson (R3/R4): waves must write FULL output cache lines.
// Half-line-per-wave patterns gave 9x WRITE_SIZE amplification.

namespace {

constexpr int S = 256, C = 64;

typedef _Float16 f16;
typedef _Float16 f16x2 __attribute__((ext_vector_type(2)));
typedef _Float16 f16x4 __attribute__((ext_vector_type(4)));
typedef _Float16 f16x8 __attribute__((ext_vector_type(8)));
typedef float f32x16 __attribute__((ext_vector_type(16)));

// ws layout (float offsets)
constexpr int OFF_KT0  = 0;        // kT0[r][j][i][{R,I}] fp32 : 32*64*64*2 = 262144
constexpr int OFF_KT1  = 262144;   // kT1 same
constexpr int OFF_FWDF = 524288;   // fwd A-frag table: 16384 f16 (8192 floats)
constexpr int OFF_INVF = 532480;   // inv A-frag table: 16384 f16 (8192 floats)

// LDS geometry: rows of 256 col-slots, 16B per col, +16B pad per 8 cols.
constexpr int P   = 4624;          // row pitch bytes
constexpr int XFO = 8 * P;         // Xf region (8 rows) after the 8 Bf/Yf rows
constexpr int LDS_BYTES = 16 * P;  // 73984 B
constexpr int SP  = 260;           // epilogue staging pitch (floats), 16B-aligned

__device__ __host__ inline int cadr(int c) { return c * 16 + (c >> 3) * 16; }

// ---- init: A-fragment tables (f16, fragment order, k = kk*16 + 8*g2 + e) ----
__global__ void k_init_frag(float* __restrict__ ws) {
  int t = blockIdx.x * 256 + threadIdx.x;  // 0..32767
  f16* fwdF = (f16*)(ws + OFF_FWDF);
  f16* invF = (f16*)(ws + OFF_INVF);
  if (t < 16384) {
    int e = t & 7, lane = (t >> 3) & 63, mtkk = t >> 9;
    int mt = mtkk & 1, kk = mtkk >> 1;
    int mc = mt * 32 + (lane & 31);
    int x = kk * 16 + 8 * (lane >> 5) + e;
    int r = mc >> 1;
    double ang = (double)((r * x) & 255) * (3.14159265358979323846 / 128.0);
    double v = (mc & 1) ? -sin(ang) : cos(ang);
    fwdF[t] = (f16)(float)v;
  } else {
    int t2 = t - 16384;
    int e = t2 & 7, lane = (t2 >> 3) & 63, mtg = (t2 >> 9) & 7, kk = t2 >> 12;
    int u = mtg * 32 + (lane & 31);
    int mcv = kk * 16 + 8 * (lane >> 5) + e;
    int r = mcv >> 1;
    double wgt = (r == 0) ? 1.0 : 2.0;
    double ang = (double)((r * u) & 255) * (3.14159265358979323846 / 128.0);
    double v = (mcv & 1) ? -wgt * sin(ang) : wgt * cos(ang);
    invF[t2] = (f16)(float)(v * (1.0 / 256.0));
  }
}

// kT[((r*64+j)*64+i)*2 + {0,1}] = {kr[r][i][j], ki[r][i][j]}  (raw)
__global__ void k_init_kT(const float* __restrict__ kr, const float* __restrict__ ki,
                          float* __restrict__ kTd) {
  int t = blockIdx.x * 256 + threadIdx.x;  // t = (r*64+j)*64+i
  int r = t >> 12, j = (t >> 6) & 63, i = t & 63;
  int src = (r * 64 + i) * 64 + j;
  kTd[2 * t + 0] = kr[src];
  kTd[2 * t + 1] = ki[src];
}

// ---- main fused kernel ----
// Block = (b, 4 slabs along the non-transformed axis), 512 threads (8 waves).
template <int DIM>
__launch_bounds__(512, 4)
__global__ void k_dim(const float* __restrict__ X, const float* __restrict__ ws,
                      float* __restrict__ out) {
  __shared__ char sm[LDS_BYTES] __attribute__((aligned(16)));

  const int tid = threadIdx.x;
  const int l = tid & 63, w = tid >> 6;
  const int g2 = l >> 5, l31 = l & 31;
  const int n0 = w * 32;                   // wave's 32-col window
  const int b = blockIdx.x >> 6;
  const int t4 = (blockIdx.x & 63) * 4;    // first slab
  const size_t bbase = (size_t)b * (S * S * C);
  const f16* fwdF = (const f16*)(ws + OFF_FWDF);
  const f16* invF = (const f16*)(ws + OFF_INVF);
  const float* kT = ws + (DIM == 0 ? OFF_KT0 : OFF_KT1);

  auto gofs = [&](int u, int c) -> size_t {
    if (DIM == 0)
      return bbase + (size_t)u * (S * C) + (size_t)(t4 + (c >> 6)) * C + (c & 63);
    else
      return bbase + (size_t)(t4 + (c >> 6)) * (S * C) + (size_t)u * C + (c & 63);
  };

  // staging assignment: wave -> (ug = w>>1 of 4 u-subrows, half = w&1 of col range)
  const int ug = w >> 1;
  const int c1 = (w & 1) * 128 + l;
  const int c2 = c1 + 64;

  float r1[8], r2[8];
  auto stage_load = [&](int u0) {
#pragma unroll
    for (int j = 0; j < 8; ++j) r1[j] = X[gofs(u0 + ug * 8 + j, c1)];
#pragma unroll
    for (int j = 0; j < 8; ++j) r2[j] = X[gofs(u0 + ug * 8 + j, c2)];
  };
  auto stage_write = [&](int buf) {
    f16x8 v1, v2;
#pragma unroll
    for (int j = 0; j < 8; ++j) { v1[j] = (f16)r1[j]; v2[j] = (f16)r2[j]; }
    char* base = sm + buf * (4 * P) + ug * P;
    *(f16x8*)(base + cadr(c1)) = v1;
    *(f16x8*)(base + cadr(c2)) = v2;
  };

  // ---------------- Phase 1: truncated DFT via MFMA ----------------
  f32x16 acc0, acc1;
#pragma unroll
  for (int q = 0; q < 16; ++q) { acc0[q] = 0.f; acc1[q] = 0.f; }

  stage_load(0);
  stage_write(0);
  __syncthreads();

  for (int ch = 0; ch < 8; ++ch) {
    if (ch < 7) stage_load((ch + 1) * 32);
    const char* bbuf = sm + (ch & 1) * (4 * P);
#pragma unroll
    for (int ks = 0; ks < 2; ++ks) {
      const int kk = ch * 2 + ks;
      f16x8 bf = *(const f16x8*)(bbuf + (ks * 2 + g2) * P + cadr(n0 + l31));
      f16x8 a0 = *(const f16x8*)(fwdF + ((size_t)(kk * 2 + 0) * 64 + l) * 8);
      f16x8 a1 = *(const f16x8*)(fwdF + ((size_t)(kk * 2 + 1) * 64 + l) * 8);
      acc0 = __builtin_amdgcn_mfma_f32_32x32x16_f16(a0, bf, acc0, 0, 0, 0);
      acc1 = __builtin_amdgcn_mfma_f32_32x32x16_f16(a1, bf, acc1, 0, 0, 0);
    }
    if (ch < 7) {
      stage_write((ch + 1) & 1);
      __syncthreads();
    }
  }

  // ---------------- Phase 2: acc -> Xf (f16, fragment-order rows) ----------------
  {
    char* xf = sm + XFO;
    const int co = cadr(n0 + l31) + 8 * g2;   // e-base = 4*g2 -> byte 8*g2
#pragma unroll
    for (int q = 0; q < 4; ++q) {
      f16x4 v0, v1;
#pragma unroll
      for (int t = 0; t < 4; ++t) { v0[t] = (f16)acc0[4 * q + t]; v1[t] = (f16)acc1[4 * q + t]; }
      *(f16x4*)(xf + q * P + co) = v0;
      *(f16x4*)(xf + (q + 4) * P + co) = v1;
    }
  }
  __syncthreads();

  // ---------------- Phase 3: complex channel mix (fp32 VALU) ----------------
  {
    const int r  = tid >> 4;
    const int i0 = (tid & 15) * 4;
    const char* xf = sm + XFO + (r >> 2) * P;
    char* yf = sm + (r >> 2) * P;
    const int eo = (r & 3) * 4;

    float yR[4][4], yI[4][4];
#pragma unroll
    for (int p = 0; p < 4; ++p)
#pragma unroll
      for (int i = 0; i < 4; ++i) { yR[p][i] = 0.f; yI[p][i] = 0.f; }

    const float4* kp = (const float4*)kT + (size_t)r * 2048 + (i0 >> 1);
#pragma unroll 2
    for (int j = 0; j < 64; ++j) {
      float4 ka = kp[j * 32 + 0];
      float4 kb = kp[j * 32 + 1];
#pragma unroll
      for (int p = 0; p < 4; ++p) {
        f16x2 x2 = *(const f16x2*)(xf + cadr(p * 64 + j) + eo);
        float xr = (float)x2[0], xi = (float)x2[1];
        yR[p][0] += ka.x * xr - ka.y * xi;  yI[p][0] += ka.x * xi + ka.y * xr;
        yR[p][1] += ka.z * xr - ka.w * xi;  yI[p][1] += ka.z * xi + ka.w * xr;
        yR[p][2] += kb.x * xr - kb.y * xi;  yI[p][2] += kb.x * xi + kb.y * xr;
        yR[p][3] += kb.z * xr - kb.w * xi;  yI[p][3] += kb.z * xi + kb.w * xr;
      }
    }
#pragma unroll
    for (int p = 0; p < 4; ++p)
#pragma unroll
      for (int i = 0; i < 4; ++i) {
        f16x2 v = {(f16)yR[p][i], (f16)yI[p][i]};
        *(f16x2*)(yf + cadr(p * 64 + i0 + i) + eo) = v;
      }
  }
  __syncthreads();

  // ---------------- Phase 4: iDFT via MFMA -> block-staged full-line stores ----
  // Per (h,mt): all waves dump 32x32 C-frags into stg[32][SP] (u_local x c),
  // barrier, then cooperative 1KB-contiguous-per-wave global writes.
  float* stg = (float*)(sm + XFO);   // 32*SP*4 = 33280 B (Xf region is free)

#pragma unroll 1
  for (int h = 0; h < 2; ++h) {
#pragma unroll 1
    for (int mt = 0; mt < 4; ++mt) {
      f32x16 a4;
#pragma unroll
      for (int q = 0; q < 16; ++q) a4[q] = 0.f;

#pragma unroll
      for (int kk = 0; kk < 4; ++kk) {
        f16x8 bf = *(const f16x8*)(sm + (kk * 2 + g2) * P + cadr(n0 + l31));
        f16x8 A = *(const f16x8*)(invF + ((size_t)(kk * 8 + h * 4 + mt) * 64 + l) * 8);
        a4 = __builtin_amdgcn_mfma_f32_32x32x16_f16(A, bf, a4, 0, 0, 0);
      }

      __syncthreads();   // previous iteration's stg reads complete
#pragma unroll
      for (int reg = 0; reg < 16; ++reg) {
        int row = (reg & 3) + 8 * (reg >> 2) + 4 * g2;
        stg[row * SP + n0 + l31] = a4[reg];
      }
      __syncthreads();   // stg tile complete

      const int u0 = (h * 4 + mt) * 32;
#pragma unroll
      for (int it = 0; it < 4; ++it) {
        const int flat = it * 512 + tid;
        if (DIM == 0) {
          // one full u-row (4 slabs x 64 ch = 1KB) per wave-instruction
          const int ur = flat >> 6;          // 0..31
          const int c4 = flat & 63;          // float4 index within row
          float4 v = *(float4*)&stg[ur * SP + c4 * 4];
          size_t g = bbase + (size_t)(u0 + ur) * (S * C) + (size_t)t4 * C + c4 * 4;
          *(float4*)&out[g] = v;
        } else {
          // 4 consecutive u x 256B = 1KB contiguous per wave-instruction
          const int p  = flat >> 9;          // slab 0..3
          const int ur = (flat >> 4) & 31;
          const int cf = flat & 15;          // float4 within 64 ch
          float4 v = *(float4*)&stg[ur * SP + p * 64 + cf * 4];
          size_t g = bbase + (size_t)(t4 + p) * (S * C) + (size_t)(u0 + ur) * C + cf * 4;
          float4 o = *(const float4*)&out[g];
          o.x += v.x; o.y += v.y; o.z += v.z; o.w += v.w;
          *(float4*)&out[g] = o;
        }
      }
    }
  }
}

}  // namespace

extern "C" void kernel_launch(void* const* d_in, const int* in_sizes, int n_in,
                              void* d_out, int out_size, void* d_ws, size_t ws_size,
                              hipStream_t stream) {
  (void)in_sizes; (void)n_in; (void)out_size; (void)ws_size;
  const float* X   = (const float*)d_in[0];
  const float* k0r = (const float*)d_in[1];
  const float* k0i = (const float*)d_in[2];
  const float* k1r = (const float*)d_in[3];
  const float* k1i = (const float*)d_in[4];
  float* out = (float*)d_out;
  float* ws  = (float*)d_ws;

  k_init_frag<<<128, 256, 0, stream>>>(ws);
  k_init_kT<<<512, 256, 0, stream>>>(k0r, k0i, ws + OFF_KT0);
  k_init_kT<<<512, 256, 0, stream>>>(k1r, k1i, ws + OFF_KT1);
  k_dim<0><<<512, 512, 0, stream>>>(X, ws, out);   // writes out
  k_dim<1><<<512, 512, 0, stream>>>(X, ws, out);   // accumulates into out
}

// Round 6
// 254.537 us; speedup vs baseline: 3.1173x; 3.1173x over previous
//
#include <hip/hip_runtime.h>

// FactorizedSpectralConv: B=8, S1=S2=256, C=64, M1=M2=32.
// Fused per-dim kernels: truncated DFT (MFMA f16) -> complex mix (VALU fp32)
// -> iDFT (MFMA f16) -> block-staged epilogue with full-line contiguous stores.
//
// R5->R6 delta: __launch_bounds__(512,4) -> (512,2). R3-R5 showed ~9x
// WRITE_SIZE amplification invariant under three different store patterns;
// hypothesis: register-cap-induced scratch spills (VGPR capped at 128 with
// ~100+ floats of live state). LDS already caps occupancy at 2 blocks/CU,
// so relaxing to a 256-VGPR budget costs nothing if the theory is right.

namespace {

constexpr int S = 256, C = 64;

typedef _Float16 f16;
typedef _Float16 f16x2 __attribute__((ext_vector_type(2)));
typedef _Float16 f16x4 __attribute__((ext_vector_type(4)));
typedef _Float16 f16x8 __attribute__((ext_vector_type(8)));
typedef float f32x16 __attribute__((ext_vector_type(16)));

// ws layout (float offsets)
constexpr int OFF_KT0  = 0;        // kT0[r][j][i][{R,I}] fp32 : 32*64*64*2 = 262144
constexpr int OFF_KT1  = 262144;   // kT1 same
constexpr int OFF_FWDF = 524288;   // fwd A-frag table: 16384 f16 (8192 floats)
constexpr int OFF_INVF = 532480;   // inv A-frag table: 16384 f16 (8192 floats)

// LDS geometry: rows of 256 col-slots, 16B per col, +16B pad per 8 cols.
constexpr int P   = 4624;          // row pitch bytes
constexpr int XFO = 8 * P;         // Xf region (8 rows) after the 8 Bf/Yf rows
constexpr int LDS_BYTES = 16 * P;  // 73984 B
constexpr int SP  = 260;           // epilogue staging pitch (floats), 16B-aligned

__device__ __host__ inline int cadr(int c) { return c * 16 + (c >> 3) * 16; }

// ---- init: A-fragment tables (f16, fragment order, k = kk*16 + 8*g2 + e) ----
__global__ void k_init_frag(float* __restrict__ ws) {
  int t = blockIdx.x * 256 + threadIdx.x;  // 0..32767
  f16* fwdF = (f16*)(ws + OFF_FWDF);
  f16* invF = (f16*)(ws + OFF_INVF);
  if (t < 16384) {
    int e = t & 7, lane = (t >> 3) & 63, mtkk = t >> 9;
    int mt = mtkk & 1, kk = mtkk >> 1;
    int mc = mt * 32 + (lane & 31);
    int x = kk * 16 + 8 * (lane >> 5) + e;
    int r = mc >> 1;
    double ang = (double)((r * x) & 255) * (3.14159265358979323846 / 128.0);
    double v = (mc & 1) ? -sin(ang) : cos(ang);
    fwdF[t] = (f16)(float)v;
  } else {
    int t2 = t - 16384;
    int e = t2 & 7, lane = (t2 >> 3) & 63, mtg = (t2 >> 9) & 7, kk = t2 >> 12;
    int u = mtg * 32 + (lane & 31);
    int mcv = kk * 16 + 8 * (lane >> 5) + e;
    int r = mcv >> 1;
    double wgt = (r == 0) ? 1.0 : 2.0;
    double ang = (double)((r * u) & 255) * (3.14159265358979323846 / 128.0);
    double v = (mcv & 1) ? -wgt * sin(ang) : wgt * cos(ang);
    invF[t2] = (f16)(float)(v * (1.0 / 256.0));
  }
}

// kT[((r*64+j)*64+i)*2 + {0,1}] = {kr[r][i][j], ki[r][i][j]}  (raw)
__global__ void k_init_kT(const float* __restrict__ kr, const float* __restrict__ ki,
                          float* __restrict__ kTd) {
  int t = blockIdx.x * 256 + threadIdx.x;  // t = (r*64+j)*64+i
  int r = t >> 12, j = (t >> 6) & 63, i = t & 63;
  int src = (r * 64 + i) * 64 + j;
  kTd[2 * t + 0] = kr[src];
  kTd[2 * t + 1] = ki[src];
}

// ---- main fused kernel ----
// Block = (b, 4 slabs along the non-transformed axis), 512 threads (8 waves).
template <int DIM>
__launch_bounds__(512, 2)
__global__ void k_dim(const float* __restrict__ X, const float* __restrict__ ws,
                      float* __restrict__ out) {
  __shared__ char sm[LDS_BYTES] __attribute__((aligned(16)));

  const int tid = threadIdx.x;
  const int l = tid & 63, w = tid >> 6;
  const int g2 = l >> 5, l31 = l & 31;
  const int n0 = w * 32;                   // wave's 32-col window
  const int b = blockIdx.x >> 6;
  const int t4 = (blockIdx.x & 63) * 4;    // first slab
  const size_t bbase = (size_t)b * (S * S * C);
  const f16* fwdF = (const f16*)(ws + OFF_FWDF);
  const f16* invF = (const f16*)(ws + OFF_INVF);
  const float* kT = ws + (DIM == 0 ? OFF_KT0 : OFF_KT1);

  auto gofs = [&](int u, int c) -> size_t {
    if (DIM == 0)
      return bbase + (size_t)u * (S * C) + (size_t)(t4 + (c >> 6)) * C + (c & 63);
    else
      return bbase + (size_t)(t4 + (c >> 6)) * (S * C) + (size_t)u * C + (c & 63);
  };

  // staging assignment: wave -> (ug = w>>1 of 4 u-subrows, half = w&1 of col range)
  const int ug = w >> 1;
  const int c1 = (w & 1) * 128 + l;
  const int c2 = c1 + 64;

  float r1[8], r2[8];
  auto stage_load = [&](int u0) {
#pragma unroll
    for (int j = 0; j < 8; ++j) r1[j] = X[gofs(u0 + ug * 8 + j, c1)];
#pragma unroll
    for (int j = 0; j < 8; ++j) r2[j] = X[gofs(u0 + ug * 8 + j, c2)];
  };
  auto stage_write = [&](int buf) {
    f16x8 v1, v2;
#pragma unroll
    for (int j = 0; j < 8; ++j) { v1[j] = (f16)r1[j]; v2[j] = (f16)r2[j]; }
    char* base = sm + buf * (4 * P) + ug * P;
    *(f16x8*)(base + cadr(c1)) = v1;
    *(f16x8*)(base + cadr(c2)) = v2;
  };

  // ---------------- Phase 1: truncated DFT via MFMA ----------------
  f32x16 acc0, acc1;
#pragma unroll
  for (int q = 0; q < 16; ++q) { acc0[q] = 0.f; acc1[q] = 0.f; }

  stage_load(0);
  stage_write(0);
  __syncthreads();

  for (int ch = 0; ch < 8; ++ch) {
    if (ch < 7) stage_load((ch + 1) * 32);
    const char* bbuf = sm + (ch & 1) * (4 * P);
#pragma unroll
    for (int ks = 0; ks < 2; ++ks) {
      const int kk = ch * 2 + ks;
      f16x8 bf = *(const f16x8*)(bbuf + (ks * 2 + g2) * P + cadr(n0 + l31));
      f16x8 a0 = *(const f16x8*)(fwdF + ((size_t)(kk * 2 + 0) * 64 + l) * 8);
      f16x8 a1 = *(const f16x8*)(fwdF + ((size_t)(kk * 2 + 1) * 64 + l) * 8);
      acc0 = __builtin_amdgcn_mfma_f32_32x32x16_f16(a0, bf, acc0, 0, 0, 0);
      acc1 = __builtin_amdgcn_mfma_f32_32x32x16_f16(a1, bf, acc1, 0, 0, 0);
    }
    if (ch < 7) {
      stage_write((ch + 1) & 1);
      __syncthreads();
    }
  }

  // ---------------- Phase 2: acc -> Xf (f16, fragment-order rows) ----------------
  {
    char* xf = sm + XFO;
    const int co = cadr(n0 + l31) + 8 * g2;   // e-base = 4*g2 -> byte 8*g2
#pragma unroll
    for (int q = 0; q < 4; ++q) {
      f16x4 v0, v1;
#pragma unroll
      for (int t = 0; t < 4; ++t) { v0[t] = (f16)acc0[4 * q + t]; v1[t] = (f16)acc1[4 * q + t]; }
      *(f16x4*)(xf + q * P + co) = v0;
      *(f16x4*)(xf + (q + 4) * P + co) = v1;
    }
  }
  __syncthreads();

  // ---------------- Phase 3: complex channel mix (fp32 VALU) ----------------
  {
    const int r  = tid >> 4;
    const int i0 = (tid & 15) * 4;
    const char* xf = sm + XFO + (r >> 2) * P;
    char* yf = sm + (r >> 2) * P;
    const int eo = (r & 3) * 4;

    float yR[4][4], yI[4][4];
#pragma unroll
    for (int p = 0; p < 4; ++p)
#pragma unroll
      for (int i = 0; i < 4; ++i) { yR[p][i] = 0.f; yI[p][i] = 0.f; }

    const float4* kp = (const float4*)kT + (size_t)r * 2048 + (i0 >> 1);
#pragma unroll 2
    for (int j = 0; j < 64; ++j) {
      float4 ka = kp[j * 32 + 0];
      float4 kb = kp[j * 32 + 1];
#pragma unroll
      for (int p = 0; p < 4; ++p) {
        f16x2 x2 = *(const f16x2*)(xf + cadr(p * 64 + j) + eo);
        float xr = (float)x2[0], xi = (float)x2[1];
        yR[p][0] += ka.x * xr - ka.y * xi;  yI[p][0] += ka.x * xi + ka.y * xr;
        yR[p][1] += ka.z * xr - ka.w * xi;  yI[p][1] += ka.z * xi + ka.w * xr;
        yR[p][2] += kb.x * xr - kb.y * xi;  yI[p][2] += kb.x * xi + kb.y * xr;
        yR[p][3] += kb.z * xr - kb.w * xi;  yI[p][3] += kb.z * xi + kb.w * xr;
      }
    }
#pragma unroll
    for (int p = 0; p < 4; ++p)
#pragma unroll
      for (int i = 0; i < 4; ++i) {
        f16x2 v = {(f16)yR[p][i], (f16)yI[p][i]};
        *(f16x2*)(yf + cadr(p * 64 + i0 + i) + eo) = v;
      }
  }
  __syncthreads();

  // ---------------- Phase 4: iDFT via MFMA -> block-staged full-line stores ----
  // Per (h,mt): all waves dump 32x32 C-frags into stg[32][SP] (u_local x c),
  // barrier, then cooperative 1KB-contiguous-per-wave global writes.
  float* stg = (float*)(sm + XFO);   // 32*SP*4 = 33280 B (Xf region is free)

#pragma unroll 1
  for (int h = 0; h < 2; ++h) {
#pragma unroll 1
    for (int mt = 0; mt < 4; ++mt) {
      f32x16 a4;
#pragma unroll
      for (int q = 0; q < 16; ++q) a4[q] = 0.f;

#pragma unroll
      for (int kk = 0; kk < 4; ++kk) {
        f16x8 bf = *(const f16x8*)(sm + (kk * 2 + g2) * P + cadr(n0 + l31));
        f16x8 A = *(const f16x8*)(invF + ((size_t)(kk * 8 + h * 4 + mt) * 64 + l) * 8);
        a4 = __builtin_amdgcn_mfma_f32_32x32x16_f16(A, bf, a4, 0, 0, 0);
      }

      __syncthreads();   // previous iteration's stg reads complete
#pragma unroll
      for (int reg = 0; reg < 16; ++reg) {
        int row = (reg & 3) + 8 * (reg >> 2) + 4 * g2;
        stg[row * SP + n0 + l31] = a4[reg];
      }
      __syncthreads();   // stg tile complete

      const int u0 = (h * 4 + mt) * 32;
#pragma unroll
      for (int it = 0; it < 4; ++it) {
        const int flat = it * 512 + tid;
        if (DIM == 0) {
          // one full u-row (4 slabs x 64 ch = 1KB) per wave-instruction
          const int ur = flat >> 6;          // 0..31
          const int c4 = flat & 63;          // float4 index within row
          float4 v = *(float4*)&stg[ur * SP + c4 * 4];
          size_t g = bbase + (size_t)(u0 + ur) * (S * C) + (size_t)t4 * C + c4 * 4;
          *(float4*)&out[g] = v;
        } else {
          // 4 consecutive u x 256B = 1KB contiguous per wave-instruction
          const int p  = flat >> 9;          // slab 0..3
          const int ur = (flat >> 4) & 31;
          const int cf = flat & 15;          // float4 within 64 ch
          float4 v = *(float4*)&stg[ur * SP + p * 64 + cf * 4];
          size_t g = bbase + (size_t)(t4 + p) * (S * C) + (size_t)(u0 + ur) * C + cf * 4;
          float4 o = *(const float4*)&out[g];
          o.x += v.x; o.y += v.y; o.z += v.z; o.w += v.w;
          *(float4*)&out[g] = o;
        }
      }
    }
  }
}

}  // namespace

extern "C" void kernel_launch(void* const* d_in, const int* in_sizes, int n_in,
                              void* d_out, int out_size, void* d_ws, size_t ws_size,
                              hipStream_t stream) {
  (void)in_sizes; (void)n_in; (void)out_size; (void)ws_size;
  const float* X   = (const float*)d_in[0];
  const float* k0r = (const float*)d_in[1];
  const float* k0i = (const float*)d_in[2];
  const float* k1r = (const float*)d_in[3];
  const float* k1i = (const float*)d_in[4];
  float* out = (float*)d_out;
  float* ws  = (float*)d_ws;

  k_init_frag<<<128, 256, 0, stream>>>(ws);
  k_init_kT<<<512, 256, 0, stream>>>(k0r, k0i, ws + OFF_KT0);
  k_init_kT<<<512, 256, 0, stream>>>(k1r, k1i, ws + OFF_KT1);
  k_dim<0><<<512, 512, 0, stream>>>(X, ws, out);   // writes out
  k_dim<1><<<512, 512, 0, stream>>>(X, ws, out);   // accumulates into out
}

// Round 7
// 199.484 us; speedup vs baseline: 3.9776x; 1.2760x over previous
//
#include <hip/hip_runtime.h>

// FactorizedSpectralConv: B=8, S1=S2=256, C=64, M1=M2=32.
// Fused per-dim kernels: truncated DFT (MFMA f16) -> complex mix (MFMA f16, R7)
// -> iDFT (MFMA f16) -> block-staged epilogue with full-line contiguous stores.
//
// MFMA mapping discipline: logical k index f(g2,e) = 8*g2 + e used for BOTH
// A (init-built tables) and B (LDS staging layout). C/D layout:
// col = lane&31, row = (reg&3) + 8*(reg>>2) + 4*(lane>>5)  [HW-verified].
//
// Lessons: R3/R4 write-amp was spills (fixed R6 via launch_bounds(512,2)).
// R7: phase-3 VALU mix + kT L2 streams -> MFMA mix with A2 fragment tables.

namespace {

constexpr int S = 256, C = 64;

typedef _Float16 f16;
typedef _Float16 f16x2 __attribute__((ext_vector_type(2)));
typedef _Float16 f16x4 __attribute__((ext_vector_type(4)));
typedef _Float16 f16x8 __attribute__((ext_vector_type(8)));
typedef float f32x16 __attribute__((ext_vector_type(16)));

// ws layout (float offsets)
constexpr int OFF_FWDF = 0;       // fwd A-frag table: 16384 f16 (8192 fl)
constexpr int OFF_INVF = 8192;    // inv A-frag table: 16384 f16 (8192 fl)
constexpr int OFF_A2   = 16384;   // mix A-frag tables: 2 dims x 524288 f16 (262144 fl each)
// total 540672 floats = 2.16 MB

// LDS geometry: rows of 256 col-slots, 16B per col, +16B pad per 8 cols.
constexpr int P   = 4624;          // row pitch bytes
constexpr int XFO = 8 * P;         // region B (Xf dump / Yt) after region A
constexpr int LDS_BYTES = 16 * P;  // 73984 B
constexpr int SP  = 260;           // epilogue staging pitch (floats)

__device__ __host__ inline int cadr(int c) { return c * 16 + (c >> 3) * 16; }

// ---- init: DFT/iDFT A-fragment tables (f16, k = kk*16 + 8*g2 + e) ----
__global__ void k_init_frag(float* __restrict__ ws) {
  int t = blockIdx.x * 256 + threadIdx.x;  // 0..32767
  f16* fwdF = (f16*)(ws + OFF_FWDF);
  f16* invF = (f16*)(ws + OFF_INVF);
  if (t < 16384) {
    int e = t & 7, lane = (t >> 3) & 63, mtkk = t >> 9;
    int mt = mtkk & 1, kk = mtkk >> 1;
    int mc = mt * 32 + (lane & 31);
    int x = kk * 16 + 8 * (lane >> 5) + e;
    int r = mc >> 1;
    double ang = (double)((r * x) & 255) * (3.14159265358979323846 / 128.0);
    double v = (mc & 1) ? -sin(ang) : cos(ang);
    fwdF[t] = (f16)(float)v;
  } else {
    int t2 = t - 16384;
    int e = t2 & 7, lane = (t2 >> 3) & 63, mtg = (t2 >> 9) & 7, kk = t2 >> 12;
    int u = mtg * 32 + (lane & 31);
    int mcv = kk * 16 + 8 * (lane >> 5) + e;
    int r = mcv >> 1;
    double wgt = (r == 0) ? 1.0 : 2.0;
    double ang = (double)((r * u) & 255) * (3.14159265358979323846 / 128.0);
    double v = (mcv & 1) ? -wgt * sin(ang) : wgt * cos(ang);
    invF[t2] = (f16)(float)(v * (1.0 / 256.0));
  }
}

// ---- init: realified mix A-frag table (per dim) ----
// A2[(((r*4+mt)*8+kk)*64+l)*8+e] = Areal[m = mt*32+(l&31)][kreal = kk*16+8*(l>>5)+e]
// Areal rows m=2i (Yr): [Kr, -Ki]; m=2i+1 (Yi): [Ki, Kr]; cols kreal = 2j+imi.
__global__ void k_init_A2(const float* __restrict__ kr, const float* __restrict__ ki,
                          f16* __restrict__ A2) {
  int t = blockIdx.x * 256 + threadIdx.x;  // 0..524287
  int e = t & 7, l = (t >> 3) & 63, kk = (t >> 9) & 7, mt = (t >> 12) & 3, r = t >> 14;
  int m = mt * 32 + (l & 31);
  int kreal = kk * 16 + 8 * (l >> 5) + e;
  int i = m >> 1, imo = m & 1, j = kreal >> 1, imi = kreal & 1;
  int src = (r * 64 + i) * 64 + j;
  float v = (imi == 0) ? ((imo == 0) ? kr[src] : ki[src])
                       : ((imo == 0) ? -ki[src] : kr[src]);
  A2[t] = (f16)v;
}

// ---- main fused kernel ----
// Block = (b, 4 slabs along the non-transformed axis), 512 threads (8 waves).
template <int DIM>
__launch_bounds__(512, 2)
__global__ void k_dim(const float* __restrict__ X, const float* __restrict__ ws,
                      float* __restrict__ out) {
  __shared__ char sm[LDS_BYTES] __attribute__((aligned(16)));

  const int tid = threadIdx.x;
  const int l = tid & 63, w = tid >> 6;
  const int g2 = l >> 5, l31 = l & 31;
  const int n0 = w * 32;                   // wave's 32-col window
  const int b = blockIdx.x >> 6;
  const int t4 = (blockIdx.x & 63) * 4;    // first slab
  const size_t bbase = (size_t)b * (S * S * C);
  const f16* fwdF = (const f16*)(ws + OFF_FWDF);
  const f16* invF = (const f16*)(ws + OFF_INVF);
  const f16* A2 = (const f16*)(ws + OFF_A2) + (DIM == 0 ? 0 : 524288);

  auto gofs = [&](int u, int c) -> size_t {
    if (DIM == 0)
      return bbase + (size_t)u * (S * C) + (size_t)(t4 + (c >> 6)) * C + (c & 63);
    else
      return bbase + (size_t)(t4 + (c >> 6)) * (S * C) + (size_t)u * C + (c & 63);
  };

  // staging assignment: wave -> (ug = w>>1 of 4 u-subrows, half = w&1 of col range)
  const int ug = w >> 1;
  const int c1 = (w & 1) * 128 + l;
  const int c2 = c1 + 64;

  float r1[8], r2[8];
  auto stage_load = [&](int u0) {
#pragma unroll
    for (int j = 0; j < 8; ++j) r1[j] = X[gofs(u0 + ug * 8 + j, c1)];
#pragma unroll
    for (int j = 0; j < 8; ++j) r2[j] = X[gofs(u0 + ug * 8 + j, c2)];
  };
  auto stage_write = [&](int buf) {
    f16x8 v1, v2;
#pragma unroll
    for (int j = 0; j < 8; ++j) { v1[j] = (f16)r1[j]; v2[j] = (f16)r2[j]; }
    char* base = sm + buf * (4 * P) + ug * P;
    *(f16x8*)(base + cadr(c1)) = v1;
    *(f16x8*)(base + cadr(c2)) = v2;
  };

  // ---------------- Phase 1: truncated DFT via MFMA ----------------
  f32x16 acc0, acc1;
#pragma unroll
  for (int q = 0; q < 16; ++q) { acc0[q] = 0.f; acc1[q] = 0.f; }

  stage_load(0);
  stage_write(0);
  __syncthreads();

  for (int ch = 0; ch < 8; ++ch) {
    if (ch < 7) stage_load((ch + 1) * 32);
    const char* bbuf = sm + (ch & 1) * (4 * P);
#pragma unroll
    for (int ks = 0; ks < 2; ++ks) {
      const int kk = ch * 2 + ks;
      f16x8 bf = *(const f16x8*)(bbuf + (ks * 2 + g2) * P + cadr(n0 + l31));
      f16x8 a0 = *(const f16x8*)(fwdF + ((size_t)(kk * 2 + 0) * 64 + l) * 8);
      f16x8 a1 = *(const f16x8*)(fwdF + ((size_t)(kk * 2 + 1) * 64 + l) * 8);
      acc0 = __builtin_amdgcn_mfma_f32_32x32x16_f16(a0, bf, acc0, 0, 0, 0);
      acc1 = __builtin_amdgcn_mfma_f32_32x32x16_f16(a1, bf, acc1, 0, 0, 0);
    }
    if (ch < 7) {
      stage_write((ch + 1) & 1);
      __syncthreads();
    }
  }

  // ---------------- Phase 2: acc -> Xf-old (region B, mc-grouped slots) ----
  {
    char* xf = sm + XFO;
    const int co = cadr(n0 + l31) + 8 * g2;   // e' base = 4*g2 -> byte 8*g2
#pragma unroll
    for (int q = 0; q < 4; ++q) {
      f16x4 v0, v1;
#pragma unroll
      for (int t = 0; t < 4; ++t) { v0[t] = (f16)acc0[4 * q + t]; v1[t] = (f16)acc1[4 * q + t]; }
      *(f16x4*)(xf + q * P + co) = v0;
      *(f16x4*)(xf + (q + 4) * P + co) = v1;
    }
  }
  __syncthreads();

  // ---------------- Phase 2.5: reshuffle Xf-old -> XfB (region A, B-frag order) ----
  // XfB word W = (r*16 + grp)*4 + p  (grp = kk*2+g2), 16B = e -> (j = kk*8+4*g2+(e>>1), im = e&1)
  {
    const char* xo = sm + XFO;
#pragma unroll
    for (int q = 0; q < 4; ++q) {
      int W = tid * 4 + q;
      int r = W >> 6, grp = (W >> 2) & 15, p = W & 3;
      int j0 = (grp >> 1) * 8 + (grp & 1) * 4;
      f16x8 vv;
#pragma unroll
      for (int e = 0; e < 8; ++e) {
        int im = e & 1, j = j0 + (e >> 1);
        int mc = 2 * r + im;
        vv[e] = *(const f16*)(xo + (mc >> 3) * P + cadr(p * 64 + j) + (mc & 7) * 2);
      }
      *(f16x8*)(sm + W * 16) = vv;
    }
  }
  __syncthreads();

  // ---------------- Phase 3: complex channel mix via MFMA ----------------
  // Wave w: modes r = w*4 + (c>>2), mt = c&3. B-frag: one ds_read_b128 from XfB
  // (cols l31<4 valid; others aliased & discarded). C -> Yt (region B, phase-4 layout).
  {
    const int colsel = l31 & 3;
#pragma unroll 1
    for (int c = 0; c < 16; ++c) {
      const int rq = c >> 2, mt = c & 3;
      const int r = w * 4 + rq;
      f32x16 acc;
#pragma unroll
      for (int q = 0; q < 16; ++q) acc[q] = 0.f;
#pragma unroll
      for (int kk = 0; kk < 8; ++kk) {
        f16x8 bf = *(const f16x8*)(sm + ((r * 16 + kk * 2 + g2) * 4 + colsel) * 16);
        f16x8 af = *(const f16x8*)(A2 + ((size_t)((r * 4 + mt) * 8 + kk) * 64 + l) * 8);
        acc = __builtin_amdgcn_mfma_f32_32x32x16_f16(af, bf, acc, 0, 0, 0);
      }
      if (l31 < 4) {
        char* yb = sm + XFO + w * P;          // g3 = r>>2 = w
        const int ebyte = rq * 4;             // e-slot = 2*rq + imo -> byte 4*rq (+2)
#pragma unroll
        for (int t2 = 0; t2 < 8; ++t2) {
          int reg = t2 * 2;
          int rowin = (reg & 3) + 8 * (reg >> 2) + 4 * g2;   // even
          int i = (mt * 32 + rowin) >> 1;
          f16x2 v2 = {(f16)acc[reg], (f16)acc[reg + 1]};
          *(f16x2*)(yb + cadr(l31 * 64 + i) + ebyte) = v2;
        }
      }
    }
  }
  __syncthreads();

  // ---------------- Phase 4: iDFT via MFMA -> block-staged full-line stores ----
  // Yt B-frags from region B; stg transpose buffer in region A.
  float* stg = (float*)sm;   // 32*SP*4 = 33280 B

#pragma unroll 1
  for (int h = 0; h < 2; ++h) {
#pragma unroll 1
    for (int mt = 0; mt < 4; ++mt) {
      f32x16 a4;
#pragma unroll
      for (int q = 0; q < 16; ++q) a4[q] = 0.f;

#pragma unroll
      for (int kk = 0; kk < 4; ++kk) {
        f16x8 bf = *(const f16x8*)(sm + XFO + (kk * 2 + g2) * P + cadr(n0 + l31));
        f16x8 A = *(const f16x8*)(invF + ((size_t)(kk * 8 + h * 4 + mt) * 64 + l) * 8);
        a4 = __builtin_amdgcn_mfma_f32_32x32x16_f16(A, bf, a4, 0, 0, 0);
      }

      __syncthreads();   // previous iteration's stg reads complete
#pragma unroll
      for (int reg = 0; reg < 16; ++reg) {
        int row = (reg & 3) + 8 * (reg >> 2) + 4 * g2;
        stg[row * SP + n0 + l31] = a4[reg];
      }
      __syncthreads();   // stg tile complete

      const int u0 = (h * 4 + mt) * 32;
#pragma unroll
      for (int it = 0; it < 4; ++it) {
        const int flat = it * 512 + tid;
        if (DIM == 0) {
          const int ur = flat >> 6;          // 0..31
          const int c4 = flat & 63;          // float4 index within 1KB row
          float4 v = *(float4*)&stg[ur * SP + c4 * 4];
          size_t g = bbase + (size_t)(u0 + ur) * (S * C) + (size_t)t4 * C + c4 * 4;
          *(float4*)&out[g] = v;
        } else {
          const int p  = flat >> 9;          // slab 0..3
          const int ur = (flat >> 4) & 31;
          const int cf = flat & 15;          // float4 within 64 ch
          float4 v = *(float4*)&stg[ur * SP + p * 64 + cf * 4];
          size_t g = bbase + (size_t)(t4 + p) * (S * C) + (size_t)(u0 + ur) * C + cf * 4;
          float4 o = *(const float4*)&out[g];
          o.x += v.x; o.y += v.y; o.z += v.z; o.w += v.w;
          *(float4*)&out[g] = o;
        }
      }
    }
  }
}

}  // namespace

extern "C" void kernel_launch(void* const* d_in, const int* in_sizes, int n_in,
                              void* d_out, int out_size, void* d_ws, size_t ws_size,
                              hipStream_t stream) {
  (void)in_sizes; (void)n_in; (void)out_size; (void)ws_size;
  const float* X   = (const float*)d_in[0];
  const float* k0r = (const float*)d_in[1];
  const float* k0i = (const float*)d_in[2];
  const float* k1r = (const float*)d_in[3];
  const float* k1i = (const float*)d_in[4];
  float* out = (float*)d_out;
  float* ws  = (float*)d_ws;
  f16* A2 = (f16*)(ws + OFF_A2);

  k_init_frag<<<128, 256, 0, stream>>>(ws);
  k_init_A2<<<2048, 256, 0, stream>>>(k0r, k0i, A2);
  k_init_A2<<<2048, 256, 0, stream>>>(k1r, k1i, A2 + 524288);
  k_dim<0><<<512, 512, 0, stream>>>(X, ws, out);   // writes out
  k_dim<1><<<512, 512, 0, stream>>>(X, ws, out);   // accumulates into out
}

// Round 8
// 174.505 us; speedup vs baseline: 4.5469x; 1.1431x over previous
//
#include <hip/hip_runtime.h>

// FactorizedSpectralConv: B=8, S1=S2=256, C=64, M1=M2=32.
// Fused per-dim kernels: truncated DFT (MFMA f16) -> complex mix (MFMA f16)
// -> iDFT (MFMA f16) -> direct fragment stores (no epilogue barriers).
//
// MFMA mapping discipline: logical k index f(g2,e) = 8*g2 + e used for BOTH
// A (init-built tables) and B (LDS staging layout). C/D layout:
// col = lane&31, row = (reg&3) + 8*(reg>>2) + 4*(lane>>5)  [HW-verified].
//
// Lessons: R3-R5 write-amp was register spills (fixed: launch_bounds(512,2));
// store granularity was never the cause -> epilogue barriers removed (R8).
// Phase-2 now writes Xf directly in mix-B fragment order (phase 2.5 deleted).

namespace {

constexpr int S = 256, C = 64;

typedef _Float16 f16;
typedef _Float16 f16x2 __attribute__((ext_vector_type(2)));
typedef _Float16 f16x4 __attribute__((ext_vector_type(4)));
typedef _Float16 f16x8 __attribute__((ext_vector_type(8)));
typedef float f32x16 __attribute__((ext_vector_type(16)));

// ws layout (float offsets)
constexpr int OFF_FWDF = 0;       // fwd A-frag table: 16384 f16 (8192 fl)
constexpr int OFF_INVF = 8192;    // inv A-frag table: 16384 f16 (8192 fl)
constexpr int OFF_A2   = 16384;   // mix A-frag tables: 2 dims x 524288 f16
// total 540672 floats = 2.16 MB

// LDS geometry: rows of 256 col-slots, 16B per col, +16B pad per 8 cols.
constexpr int P   = 4624;          // row pitch bytes
constexpr int XFO = 8 * P;         // region B (Yt) after region A (staging/XfB)
constexpr int LDS_BYTES = 16 * P;  // 73984 B

__device__ __host__ inline int cadr(int c) { return c * 16 + (c >> 3) * 16; }

// ---- init: DFT/iDFT A-fragment tables (f16, k = kk*16 + 8*g2 + e) ----
__global__ void k_init_frag(float* __restrict__ ws) {
  int t = blockIdx.x * 256 + threadIdx.x;  // 0..32767
  f16* fwdF = (f16*)(ws + OFF_FWDF);
  f16* invF = (f16*)(ws + OFF_INVF);
  if (t < 16384) {
    int e = t & 7, lane = (t >> 3) & 63, mtkk = t >> 9;
    int mt = mtkk & 1, kk = mtkk >> 1;
    int mc = mt * 32 + (lane & 31);
    int x = kk * 16 + 8 * (lane >> 5) + e;
    int r = mc >> 1;
    double ang = (double)((r * x) & 255) * (3.14159265358979323846 / 128.0);
    double v = (mc & 1) ? -sin(ang) : cos(ang);
    fwdF[t] = (f16)(float)v;
  } else {
    int t2 = t - 16384;
    int e = t2 & 7, lane = (t2 >> 3) & 63, mtg = (t2 >> 9) & 7, kk = t2 >> 12;
    int u = mtg * 32 + (lane & 31);
    int mcv = kk * 16 + 8 * (lane >> 5) + e;
    int r = mcv >> 1;
    double wgt = (r == 0) ? 1.0 : 2.0;
    double ang = (double)((r * u) & 255) * (3.14159265358979323846 / 128.0);
    double v = (mcv & 1) ? -wgt * sin(ang) : wgt * cos(ang);
    invF[t2] = (f16)(float)(v * (1.0 / 256.0));
  }
}

// ---- init: realified mix A-frag table (per dim) ----
// A2[(((r*4+mt)*8+kk)*64+l)*8+e] = Areal[m = mt*32+(l&31)][kreal = kk*16+8*(l>>5)+e]
// Areal rows m=2i (Yr): [Kr, -Ki]; m=2i+1 (Yi): [Ki, Kr]; cols kreal = 2j+imi.
__global__ void k_init_A2(const float* __restrict__ kr, const float* __restrict__ ki,
                          f16* __restrict__ A2) {
  int t = blockIdx.x * 256 + threadIdx.x;  // 0..524287
  int e = t & 7, l = (t >> 3) & 63, kk = (t >> 9) & 7, mt = (t >> 12) & 3, r = t >> 14;
  int m = mt * 32 + (l & 31);
  int kreal = kk * 16 + 8 * (l >> 5) + e;
  int i = m >> 1, imo = m & 1, j = kreal >> 1, imi = kreal & 1;
  int src = (r * 64 + i) * 64 + j;
  float v = (imi == 0) ? ((imo == 0) ? kr[src] : ki[src])
                       : ((imo == 0) ? -ki[src] : kr[src]);
  A2[t] = (f16)v;
}

// ---- main fused kernel ----
// Block = (b, 4 slabs along the non-transformed axis), 512 threads (8 waves).
template <int DIM>
__launch_bounds__(512, 2)
__global__ void k_dim(const float* __restrict__ X, const float* __restrict__ ws,
                      float* __restrict__ out) {
  __shared__ char sm[LDS_BYTES] __attribute__((aligned(16)));

  const int tid = threadIdx.x;
  const int l = tid & 63, w = tid >> 6;
  const int g2 = l >> 5, l31 = l & 31;
  const int n0 = w * 32;                   // wave's 32-col window
  const int b = blockIdx.x >> 6;
  const int t4 = (blockIdx.x & 63) * 4;    // first slab
  const size_t bbase = (size_t)b * (S * S * C);
  const f16* fwdF = (const f16*)(ws + OFF_FWDF);
  const f16* invF = (const f16*)(ws + OFF_INVF);
  const f16* A2 = (const f16*)(ws + OFF_A2) + (DIM == 0 ? 0 : 524288);

  auto gofs = [&](int u, int c) -> size_t {
    if (DIM == 0)
      return bbase + (size_t)u * (S * C) + (size_t)(t4 + (c >> 6)) * C + (c & 63);
    else
      return bbase + (size_t)(t4 + (c >> 6)) * (S * C) + (size_t)u * C + (c & 63);
  };

  // staging assignment: wave -> (ug = w>>1 of 4 u-subrows, half = w&1 of col range)
  const int ug = w >> 1;
  const int c1 = (w & 1) * 128 + l;
  const int c2 = c1 + 64;

  float r1[8], r2[8];
  auto stage_load = [&](int u0) {
#pragma unroll
    for (int j = 0; j < 8; ++j) r1[j] = X[gofs(u0 + ug * 8 + j, c1)];
#pragma unroll
    for (int j = 0; j < 8; ++j) r2[j] = X[gofs(u0 + ug * 8 + j, c2)];
  };
  auto stage_write = [&](int buf) {
    f16x8 v1, v2;
#pragma unroll
    for (int j = 0; j < 8; ++j) { v1[j] = (f16)r1[j]; v2[j] = (f16)r2[j]; }
    char* base = sm + buf * (4 * P) + ug * P;
    *(f16x8*)(base + cadr(c1)) = v1;
    *(f16x8*)(base + cadr(c2)) = v2;
  };

  // ---------------- Phase 1: truncated DFT via MFMA ----------------
  f32x16 acc0, acc1;
#pragma unroll
  for (int q = 0; q < 16; ++q) { acc0[q] = 0.f; acc1[q] = 0.f; }

  stage_load(0);
  stage_write(0);
  __syncthreads();

  for (int ch = 0; ch < 8; ++ch) {
    if (ch < 7) stage_load((ch + 1) * 32);
    const char* bbuf = sm + (ch & 1) * (4 * P);
#pragma unroll
    for (int ks = 0; ks < 2; ++ks) {
      const int kk = ch * 2 + ks;
      f16x8 bf = *(const f16x8*)(bbuf + (ks * 2 + g2) * P + cadr(n0 + l31));
      f16x8 a0 = *(const f16x8*)(fwdF + ((size_t)(kk * 2 + 0) * 64 + l) * 8);
      f16x8 a1 = *(const f16x8*)(fwdF + ((size_t)(kk * 2 + 1) * 64 + l) * 8);
      acc0 = __builtin_amdgcn_mfma_f32_32x32x16_f16(a0, bf, acc0, 0, 0, 0);
      acc1 = __builtin_amdgcn_mfma_f32_32x32x16_f16(a1, bf, acc1, 0, 0, 0);
    }
    if (ch < 7) {
      stage_write((ch + 1) & 1);
      __syncthreads();
    }
  }
  __syncthreads();   // region A (staging) now safe to overwrite with XfB

  // ---------------- Phase 2: acc -> XfB directly (region A, B-frag order) ----
  // Word W = (r*16 + kk*2 + g2p)*4 + p at byte W*16 + (W>>3)*16 (pad: conflict-free).
  // acc reg pairs (2t, 2t+1) = (re, im) of mode r = (mc_even)>>1.
  {
    const int col = n0 + l31;
    const int p = col >> 6, j = col & 63;
    const int kk = j >> 3, g2p = (j >> 2) & 1, js = j & 3;
#pragma unroll
    for (int pr = 0; pr < 16; ++pr) {
      const int q = (pr & 7) >> 1, hf = pr & 1;
      const int r = 2 * g2 + 4 * q + hf + (pr >> 3) * 16;
      const int reg = 4 * q + 2 * hf;
      const float v0 = (pr < 8) ? acc0[reg] : acc1[reg];
      const float v1 = (pr < 8) ? acc0[reg + 1] : acc1[reg + 1];
      f16x2 v2 = {(f16)v0, (f16)v1};
      const int W = (r * 16 + kk * 2 + g2p) * 4 + p;
      *(f16x2*)(sm + W * 16 + (W >> 3) * 16 + js * 4) = v2;
    }
  }
  __syncthreads();

  // ---------------- Phase 3: complex channel mix via MFMA ----------------
  // Wave w: modes r = w*4 + (c>>2), mt = c&3. C -> Yt (region B, phase-4 layout).
  {
    const int colsel = l31 & 3;
#pragma unroll 1
    for (int c = 0; c < 16; ++c) {
      const int rq = c >> 2, mt = c & 3;
      const int r = w * 4 + rq;
      f32x16 acc;
#pragma unroll
      for (int q = 0; q < 16; ++q) acc[q] = 0.f;
#pragma unroll
      for (int kk = 0; kk < 8; ++kk) {
        const int W = (r * 16 + kk * 2 + g2) * 4 + colsel;
        f16x8 bf = *(const f16x8*)(sm + W * 16 + (W >> 3) * 16);
        f16x8 af = *(const f16x8*)(A2 + ((size_t)((r * 4 + mt) * 8 + kk) * 64 + l) * 8);
        acc = __builtin_amdgcn_mfma_f32_32x32x16_f16(af, bf, acc, 0, 0, 0);
      }
      if (l31 < 4) {
        char* yb = sm + XFO + w * P;          // row g3 = r>>2 = w
        const int ebyte = rq * 4;             // e-slot = 2*rq + imo -> byte 4*rq (+2)
#pragma unroll
        for (int t2 = 0; t2 < 8; ++t2) {
          int reg = t2 * 2;
          int rowin = (reg & 3) + 8 * (reg >> 2) + 4 * g2;   // even
          int i = (mt * 32 + rowin) >> 1;
          f16x2 v2 = {(f16)acc[reg], (f16)acc[reg + 1]};
          *(f16x2*)(yb + cadr(l31 * 64 + i) + ebyte) = v2;
        }
      }
    }
  }
  __syncthreads();

  // ---------------- Phase 4: iDFT via MFMA -> direct fragment stores ----
  // No barriers: Yt (region B) is read-only here; waves fully independent.
  const int colg = n0 + l31;
  const int pp = colg >> 6, jj = colg & 63;
#pragma unroll 1
  for (int h = 0; h < 2; ++h) {
#pragma unroll 1
    for (int mt = 0; mt < 4; ++mt) {
      f32x16 a4;
#pragma unroll
      for (int q = 0; q < 16; ++q) a4[q] = 0.f;

#pragma unroll
      for (int kk = 0; kk < 4; ++kk) {
        f16x8 bf = *(const f16x8*)(sm + XFO + (kk * 2 + g2) * P + cadr(colg));
        f16x8 A = *(const f16x8*)(invF + ((size_t)(kk * 8 + h * 4 + mt) * 64 + l) * 8);
        a4 = __builtin_amdgcn_mfma_f32_32x32x16_f16(A, bf, a4, 0, 0, 0);
      }

      const int u0 = (h * 4 + mt) * 32;
#pragma unroll
      for (int reg = 0; reg < 16; ++reg) {
        const int u = u0 + (reg & 3) + 8 * (reg >> 2) + 4 * g2;
        size_t g = (DIM == 0)
                       ? bbase + (size_t)u * (S * C) + (size_t)(t4 + pp) * C + jj
                       : bbase + (size_t)(t4 + pp) * (S * C) + (size_t)u * C + jj;
        if (DIM == 0) out[g] = a4[reg];
        else          out[g] += a4[reg];
      }
    }
  }
}

}  // namespace

extern "C" void kernel_launch(void* const* d_in, const int* in_sizes, int n_in,
                              void* d_out, int out_size, void* d_ws, size_t ws_size,
                              hipStream_t stream) {
  (void)in_sizes; (void)n_in; (void)out_size; (void)ws_size;
  const float* X   = (const float*)d_in[0];
  const float* k0r = (const float*)d_in[1];
  const float* k0i = (const float*)d_in[2];
  const float* k1r = (const float*)d_in[3];
  const float* k1i = (const float*)d_in[4];
  float* out = (float*)d_out;
  float* ws  = (float*)d_ws;
  f16* A2 = (f16*)(ws + OFF_A2);

  k_init_frag<<<128, 256, 0, stream>>>(ws);
  k_init_A2<<<2048, 256, 0, stream>>>(k0r, k0i, A2);
  k_init_A2<<<2048, 256, 0, stream>>>(k1r, k1i, A2 + 524288);
  k_dim<0><<<512, 512, 0, stream>>>(X, ws, out);   // writes out
  k_dim<1><<<512, 512, 0, stream>>>(X, ws, out);   // accumulates into out
}